// Round 4
// baseline (2372.882 us; speedup 1.0000x reference)
//
#include <hip/hip_runtime.h>
#include <math.h>

#define NN 50000
#define FIN 300
constexpr float ALPHA_C = 0.5f;
constexpr float BETA_C  = 0.09531017980432486f;  // log(1.1)
constexpr float NEG_SLOPE = 0.2f;

// ---------------- CSR build ----------------
__global__ void hist_kernel(const int* __restrict__ dst, int* __restrict__ deg, int E) {
    int e = blockIdx.x * blockDim.x + threadIdx.x;
    if (e < E) atomicAdd(&deg[dst[e]], 1);
}

__global__ void scan_kernel(const int* __restrict__ deg, int* __restrict__ rowptr, int n) {
    __shared__ int sh[1024];
    __shared__ int carry;
    if (threadIdx.x == 0) { carry = 0; rowptr[0] = 0; }
    __syncthreads();
    for (int base = 0; base < n; base += 1024) {
        int i = base + threadIdx.x;
        int v = (i < n) ? deg[i] : 0;
        sh[threadIdx.x] = v;
        __syncthreads();
        for (int off = 1; off < 1024; off <<= 1) {
            int t = (threadIdx.x >= off) ? sh[threadIdx.x - off] : 0;
            __syncthreads();
            sh[threadIdx.x] += t;
            __syncthreads();
        }
        if (i < n) rowptr[i + 1] = sh[threadIdx.x] + carry;
        __syncthreads();
        if (threadIdx.x == 0) carry += sh[1023];
        __syncthreads();
    }
}

__global__ void dinv_kernel(const int* __restrict__ deg, float* __restrict__ dinv, int n) {
    int i = blockIdx.x * blockDim.x + threadIdx.x;
    if (i < n) dinv[i] = rsqrtf((float)deg[i] + 1.0f);
}

__global__ void copy_int_kernel(const int* __restrict__ a, int* __restrict__ b, int n) {
    int i = blockIdx.x * blockDim.x + threadIdx.x;
    if (i < n) b[i] = a[i];
}

__global__ void fill_kernel(const int* __restrict__ src, const int* __restrict__ dst,
                            const float* __restrict__ dinv, int* __restrict__ cursor,
                            int* __restrict__ csr_src, float* __restrict__ csr_w, int E) {
    int e = blockIdx.x * blockDim.x + threadIdx.x;
    if (e < E) {
        int s = src[e], d = dst[e];
        int p = atomicAdd(&cursor[d], 1);
        csr_src[p] = s;
        csr_w[p]   = dinv[s] * dinv[d];
    }
}

// ---------------- GEMM: C = cAB*(A@W) + cA*A + bias ----------------
__global__ __launch_bounds__(256)
void gemm_kernel(const float* __restrict__ A, const float* __restrict__ W,
                 float* __restrict__ C, int n, int K, int M,
                 float cAB, float cA, const float* __restrict__ bias) {
    __shared__ float As[16][65];
    __shared__ float Ws[16][64];
    int rowBase = blockIdx.x * 64, colBase = blockIdx.y * 64;
    int tid = threadIdx.x;
    int tx = tid & 15, ty = tid >> 4;
    float acc[4][4] = {};
    for (int k0 = 0; k0 < K; k0 += 16) {
        for (int idx = tid; idx < 64 * 16; idx += 256) {
            int m = idx >> 4, k = idx & 15;
            int r = rowBase + m, kk = k0 + k;
            As[k][m] = (r < n && kk < K) ? A[(long)r * K + kk] : 0.f;
        }
        for (int idx = tid; idx < 16 * 64; idx += 256) {
            int k = idx >> 6, c = idx & 63;
            int kk = k0 + k, cc = colBase + c;
            Ws[k][c] = (kk < K && cc < M) ? W[(long)kk * M + cc] : 0.f;
        }
        __syncthreads();
#pragma unroll
        for (int k = 0; k < 16; ++k) {
            float a0[4], b0[4];
#pragma unroll
            for (int i = 0; i < 4; i++) a0[i] = As[k][ty * 4 + i];
#pragma unroll
            for (int j = 0; j < 4; j++) b0[j] = Ws[k][tx * 4 + j];
#pragma unroll
            for (int i = 0; i < 4; i++)
#pragma unroll
                for (int j = 0; j < 4; j++) acc[i][j] += a0[i] * b0[j];
        }
        __syncthreads();
    }
#pragma unroll
    for (int i = 0; i < 4; i++) {
        int r = rowBase + ty * 4 + i;
        if (r >= n) continue;
#pragma unroll
        for (int j = 0; j < 4; j++) {
            int c = colBase + tx * 4 + j;
            if (c >= M) continue;
            float v = cAB * acc[i][j];
            if (cA != 0.f) v += cA * A[(long)r * K + c];  // only used when M==K
            if (bias) v += bias[c];
            C[(long)r * M + c] = v;
        }
    }
}

// ---------------- prop: out = cP*(D^-1/2 A D^-1/2 h) + cH*h + bias ----------------
__global__ __launch_bounds__(256)
void prop_kernel(const float* __restrict__ h, float* __restrict__ out,
                 const int* __restrict__ rowptr, const int* __restrict__ csr_src,
                 const float* __restrict__ csr_w, const float* __restrict__ dinv,
                 const float* __restrict__ bias, int n, int D4, float cP, float cH) {
    int i = (blockIdx.x * blockDim.x + threadIdx.x) >> 6;
    int lane = threadIdx.x & 63;
    if (i >= n) return;
    const float4* h4 = (const float4*)h;
    int c0 = lane, c1 = lane + 64;
    bool a0 = c0 < D4, a1 = c1 < D4;
    float4 acc0 = {0, 0, 0, 0}, acc1 = {0, 0, 0, 0};
    float sw = dinv[i] * dinv[i];
    long bi = (long)i * D4;
    if (a0) { float4 v = h4[bi + c0]; acc0.x = sw * v.x; acc0.y = sw * v.y; acc0.z = sw * v.z; acc0.w = sw * v.w; }
    if (a1) { float4 v = h4[bi + c1]; acc1.x = sw * v.x; acc1.y = sw * v.y; acc1.z = sw * v.z; acc1.w = sw * v.w; }
    int p0 = rowptr[i], p1 = rowptr[i + 1];
    for (int p = p0; p < p1; ++p) {
        int s = csr_src[p];
        float w = csr_w[p];
        long bs = (long)s * D4;
        if (a0) { float4 v = h4[bs + c0]; acc0.x += w * v.x; acc0.y += w * v.y; acc0.z += w * v.z; acc0.w += w * v.w; }
        if (a1) { float4 v = h4[bs + c1]; acc1.x += w * v.x; acc1.y += w * v.y; acc1.z += w * v.z; acc1.w += w * v.w; }
    }
    float4* o4 = (float4*)out;
    if (a0) {
        float4 r = {cP * acc0.x, cP * acc0.y, cP * acc0.z, cP * acc0.w};
        if (cH != 0.f) { float4 v = h4[bi + c0]; r.x += cH * v.x; r.y += cH * v.y; r.z += cH * v.z; r.w += cH * v.w; }
        if (bias) { float4 b = ((const float4*)bias)[c0]; r.x += b.x; r.y += b.y; r.z += b.z; r.w += b.w; }
        o4[bi + c0] = r;
    }
    if (a1) {
        float4 r = {cP * acc1.x, cP * acc1.y, cP * acc1.z, cP * acc1.w};
        if (cH != 0.f) { float4 v = h4[bi + c1]; r.x += cH * v.x; r.y += cH * v.y; r.z += cH * v.z; r.w += cH * v.w; }
        if (bias) { float4 b = ((const float4*)bias)[c1]; r.x += b.x; r.y += b.y; r.z += b.z; r.w += b.w; }
        o4[bi + c1] = r;
    }
}

// ---------------- GATv2 ----------------
__device__ inline float lrelu(float x) { return x > 0.f ? x : NEG_SLOPE * x; }

__global__ __launch_bounds__(256)
void gat_logits_kernel(const float* __restrict__ xl, const float* __restrict__ xr,
                       const float* __restrict__ att, const int* __restrict__ rowptr,
                       const int* __restrict__ csr_src, float* __restrict__ logits,
                       float* __restrict__ self_logits, int n) {
    int t = blockIdx.x * blockDim.x + threadIdx.x;
    int i = t >> 1, hh = t & 1;
    if (i >= n) return;
    float4 attv[8], xrv[8];
    const float4* att4 = (const float4*)att;
    const float4* xr4 = (const float4*)xr;
#pragma unroll
    for (int c = 0; c < 8; c++) {
        attv[c] = att4[hh * 8 + c];
        xrv[c]  = xr4[(long)i * 16 + hh * 8 + c];
    }
    const float4* xl4 = (const float4*)xl;
    // self edge
    {
        float s = 0.f;
        long b = (long)i * 16 + hh * 8;
#pragma unroll
        for (int c = 0; c < 8; c++) {
            float4 e = xl4[b + c];
            s += lrelu(e.x + xrv[c].x) * attv[c].x;
            s += lrelu(e.y + xrv[c].y) * attv[c].y;
            s += lrelu(e.z + xrv[c].z) * attv[c].z;
            s += lrelu(e.w + xrv[c].w) * attv[c].w;
        }
        self_logits[i * 2 + hh] = s;
    }
    int p0 = rowptr[i], p1 = rowptr[i + 1];
    for (int p = p0; p < p1; ++p) {
        int sn = csr_src[p];
        long b = (long)sn * 16 + hh * 8;
        float s = 0.f;
#pragma unroll
        for (int c = 0; c < 8; c++) {
            float4 e = xl4[b + c];
            s += lrelu(e.x + xrv[c].x) * attv[c].x;
            s += lrelu(e.y + xrv[c].y) * attv[c].y;
            s += lrelu(e.z + xrv[c].z) * attv[c].z;
            s += lrelu(e.w + xrv[c].w) * attv[c].w;
        }
        logits[(long)p * 2 + hh] = s;
    }
}

__global__ __launch_bounds__(256)
void gat_mden_kernel(const float* __restrict__ logits, const float* __restrict__ self_logits,
                     const int* __restrict__ rowptr, float* __restrict__ m_arr,
                     float* __restrict__ den_arr, int n) {
    int t = blockIdx.x * blockDim.x + threadIdx.x;
    int i = t >> 1, hh = t & 1;
    if (i >= n) return;
    int p0 = rowptr[i], p1 = rowptr[i + 1];
    float m = self_logits[i * 2 + hh];
    for (int p = p0; p < p1; ++p) m = fmaxf(m, logits[(long)p * 2 + hh]);
    float den = expf(self_logits[i * 2 + hh] - m);
    for (int p = p0; p < p1; ++p) den += expf(logits[(long)p * 2 + hh] - m);
    m_arr[i * 2 + hh] = m;
    den_arr[i * 2 + hh] = den;
}

__global__ __launch_bounds__(256)
void gat_out_kernel(const float* __restrict__ xl, const int* __restrict__ rowptr,
                    const int* __restrict__ csr_src, const float* __restrict__ logits,
                    const float* __restrict__ self_logits, const float* __restrict__ m_arr,
                    const float* __restrict__ den_arr, const float* __restrict__ bias,
                    float* __restrict__ out, int n) {
    int i = (blockIdx.x * blockDim.x + threadIdx.x) >> 6;
    int lane = threadIdx.x & 63;
    if (i >= n) return;
    int hh = lane >> 5;
    float m = m_arr[i * 2 + hh];
    float inv = 1.f / (den_arr[i * 2 + hh] + 1e-16f);
    float acc = expf(self_logits[i * 2 + hh] - m) * inv * xl[(long)i * 64 + lane];
    int p0 = rowptr[i], p1 = rowptr[i + 1];
    for (int p = p0; p < p1; ++p) {
        float w = expf(logits[(long)p * 2 + hh] - m) * inv;
        acc += w * xl[(long)csr_src[p] * 64 + lane];
    }
    out[(long)i * 64 + lane] = fmaxf(acc + bias[lane], 0.f);  // bias + ReLU fused
}

__global__ void sigmoid_kernel(const float* __restrict__ in, float* __restrict__ out, int n4) {
    int i = blockIdx.x * blockDim.x + threadIdx.x;
    if (i < n4) {
        float4 v = ((const float4*)in)[i];
        float4 r;
        r.x = 1.f / (1.f + expf(-v.x));
        r.y = 1.f / (1.f + expf(-v.y));
        r.z = 1.f / (1.f + expf(-v.z));
        r.w = 1.f / (1.f + expf(-v.w));
        ((float4*)out)[i] = r;
    }
}

// ---------------- launch ----------------
extern "C" void kernel_launch(void* const* d_in, const int* in_sizes, int n_in,
                              void* d_out, int out_size, void* d_ws, size_t ws_size,
                              hipStream_t stream) {
    const int N = NN;
    const int E = in_sizes[1] / 2;

    // Workspace requirement (bytes). If the harness scratch is smaller than
    // this, launching would OOB-write d_ws and can fault the GPU; bail out
    // cleanly instead (output stays zero -> visible absmax failure, no crash).
    size_t need = 0;
    need += (size_t)N * 304 * 4 * 2;     // bufA, bufB
    need += (size_t)E * 4;               // csr_w
    need += (size_t)E * 2 * 4;           // logits
    need += (size_t)N * 2 * 4 * 3;       // self_logits, m_arr, den_arr
    need += (size_t)N * 4;               // dinv
    need += (size_t)N * 4;               // deg
    need += (size_t)(N + 4) * 4;         // rowptr
    need += (size_t)N * 4;               // cursor
    need += (size_t)E * 4;               // csr_src
    if (ws_size < need) return;

    const float* x      = (const float*)d_in[0];
    const int*   ei     = (const int*)d_in[1];
    const int*   e_src  = ei;
    const int*   e_dst  = ei + E;
    const float* W1  = (const float*)d_in[2];  const float* b1  = (const float*)d_in[3];
    const float* W2  = (const float*)d_in[4];
    const float* W3  = (const float*)d_in[5];  const float* b3  = (const float*)d_in[6];
    const float* W4  = (const float*)d_in[7];  const float* b4  = (const float*)d_in[8];
    const float* W5  = (const float*)d_in[9];  const float* b5  = (const float*)d_in[10];
    const float* Wl  = (const float*)d_in[11];
    const float* Wr  = (const float*)d_in[12];
    const float* attw= (const float*)d_in[13];
    const float* bg  = (const float*)d_in[14];
    const float* Wd1 = (const float*)d_in[15]; const float* bd1 = (const float*)d_in[16];
    const float* Wd2 = (const float*)d_in[17]; const float* bd2 = (const float*)d_in[18];
    const float* Wd3 = (const float*)d_in[19];
    const float* Wd4 = (const float*)d_in[20]; const float* bd4 = (const float*)d_in[21];

    // workspace carve-up
    char* w = (char*)d_ws;
    float* bufA = (float*)w;                 w += (size_t)N * 304 * 4;   // keep 16B-aligned rows
    float* bufB = (float*)w;                 w += (size_t)N * 304 * 4;
    float* csr_w = (float*)w;                w += (size_t)E * 4;
    float* logits = (float*)w;               w += (size_t)E * 2 * 4;
    float* self_logits = (float*)w;          w += (size_t)N * 2 * 4;
    float* m_arr = (float*)w;                w += (size_t)N * 2 * 4;
    float* den_arr = (float*)w;              w += (size_t)N * 2 * 4;
    float* dinv = (float*)w;                 w += (size_t)N * 4;
    int* deg = (int*)w;                      w += (size_t)N * 4;
    int* rowptr = (int*)w;                   w += (size_t)(N + 4) * 4;
    int* cursor = (int*)w;                   w += (size_t)N * 4;
    int* csr_src = (int*)w;                  w += (size_t)E * 4;
    float* T = (float*)d_out;                // GEMM tmp buffer (N x <=300)

    int nb_e = (E + 255) / 256;
    int nb_n = (N + 255) / 256;
    int nb_wave = (N + 3) / 4;      // wave-per-node kernels, 4 waves/block
    int nb_2n = (2 * N + 255) / 256;

    // --- CSR build ---
    hipMemsetAsync(deg, 0, (size_t)N * 4, stream);
    hist_kernel<<<nb_e, 256, 0, stream>>>(e_dst, deg, E);
    scan_kernel<<<1, 1024, 0, stream>>>(deg, rowptr, N);
    dinv_kernel<<<nb_n, 256, 0, stream>>>(deg, dinv, N);
    copy_int_kernel<<<nb_n, 256, 0, stream>>>(rowptr, cursor, N);
    fill_kernel<<<nb_e, 256, 0, stream>>>(e_src, e_dst, dinv, cursor, csr_src, csr_w, E);

    const int GR = (N + 63) / 64;  // gemm row-blocks
    auto gemm = [&](const float* A, const float* W, float* C, int K, int M,
                    float cAB, float cA, const float* bias) {
        dim3 grid(GR, (M + 63) / 64);
        gemm_kernel<<<grid, 256, 0, stream>>>(A, W, C, N, K, M, cAB, cA, bias);
    };
    auto prop = [&](const float* h, float* out, int D, float cP, float cH, const float* bias) {
        prop_kernel<<<nb_wave, 256, 0, stream>>>(h, out, rowptr, csr_src, csr_w, dinv,
                                                 bias, N, D / 4, cP, cH);
    };

    // L1: gcn(x, W1, b1) -> A [256]
    gemm(x, W1, T, FIN, 256, 1.f, 0.f, nullptr);
    prop(T, bufA, 256, 1.f, 0.f, b1);
    // L2: gcn2(A, W2) -> A  (hp in B)
    prop(bufA, bufB, 256, 1.f - ALPHA_C, ALPHA_C, nullptr);
    gemm(bufB, W2, bufA, 256, 256, BETA_C, 1.f - BETA_C, nullptr);
    // L3: gcn(A, W3, b3) -> B [128]
    gemm(bufA, W3, T, 256, 128, 1.f, 0.f, nullptr);
    prop(T, bufB, 128, 1.f, 0.f, b3);
    // L4: gcn(B, W4, b4) -> A [64]
    gemm(bufB, W4, T, 128, 64, 1.f, 0.f, nullptr);
    prop(T, bufA, 64, 1.f, 0.f, b4);
    // L5: gcn(A, W5, b5) -> B [32]
    gemm(bufA, W5, T, 64, 32, 1.f, 0.f, nullptr);
    prop(T, bufB, 32, 1.f, 0.f, b5);
    // GAT: xl = B@Wl -> A, xr = B@Wr -> T
    gemm(bufB, Wl, bufA, 32, 64, 1.f, 0.f, nullptr);
    gemm(bufB, Wr, T, 32, 64, 1.f, 0.f, nullptr);
    gat_logits_kernel<<<nb_2n, 256, 0, stream>>>(bufA, T, attw, rowptr, csr_src,
                                                 logits, self_logits, N);
    gat_mden_kernel<<<nb_2n, 256, 0, stream>>>(logits, self_logits, rowptr, m_arr, den_arr, N);
    gat_out_kernel<<<nb_wave, 256, 0, stream>>>(bufA, rowptr, csr_src, logits, self_logits,
                                                m_arr, den_arr, bg, bufB, N);  // + ReLU -> B [64]
    // dec1: gcn(B, Wd1, bd1) -> A [128]
    gemm(bufB, Wd1, T, 64, 128, 1.f, 0.f, nullptr);
    prop(T, bufA, 128, 1.f, 0.f, bd1);
    // dec2: gcn(A, Wd2, bd2) -> B [256]
    gemm(bufA, Wd2, T, 128, 256, 1.f, 0.f, nullptr);
    prop(T, bufB, 256, 1.f, 0.f, bd2);
    // dec3: gcn2(B, Wd3) -> B (hp in A)
    prop(bufB, bufA, 256, 1.f - ALPHA_C, ALPHA_C, nullptr);
    gemm(bufA, Wd3, bufB, 256, 256, BETA_C, 1.f - BETA_C, nullptr);
    // dec4: gcn(B, Wd4, bd4) -> A [300]
    gemm(bufB, Wd4, T, 256, FIN, 1.f, 0.f, nullptr);
    prop(T, bufA, FIN, 1.f, 0.f, bd4);
    // sigmoid -> d_out
    sigmoid_kernel<<<(out_size / 4 + 255) / 256, 256, 0, stream>>>(bufA, (float*)d_out, out_size / 4);
}

// Round 5
// 1918.824 us; speedup vs baseline: 1.2366x; 1.2366x over previous
//
#include <hip/hip_runtime.h>
#include <math.h>

#define NN 50000
#define FIN 300
constexpr float ALPHA_C = 0.5f;
constexpr float BETA_C  = 0.09531017980432486f;  // log(1.1)
constexpr float NEG_SLOPE = 0.2f;

typedef unsigned short u16;
typedef __attribute__((ext_vector_type(8))) short short8;
typedef __attribute__((ext_vector_type(4))) float f32x4;

// ---------------- CSR build ----------------
__global__ void hist_kernel(const int* __restrict__ dst, int* __restrict__ deg, int E) {
    int e = blockIdx.x * blockDim.x + threadIdx.x;
    if (e < E) atomicAdd(&deg[dst[e]], 1);
}

__global__ void scan_kernel(const int* __restrict__ deg, int* __restrict__ rowptr, int n) {
    __shared__ int sh[1024];
    __shared__ int carry;
    if (threadIdx.x == 0) { carry = 0; rowptr[0] = 0; }
    __syncthreads();
    for (int base = 0; base < n; base += 1024) {
        int i = base + threadIdx.x;
        int v = (i < n) ? deg[i] : 0;
        sh[threadIdx.x] = v;
        __syncthreads();
        for (int off = 1; off < 1024; off <<= 1) {
            int t = (threadIdx.x >= off) ? sh[threadIdx.x - off] : 0;
            __syncthreads();
            sh[threadIdx.x] += t;
            __syncthreads();
        }
        if (i < n) rowptr[i + 1] = sh[threadIdx.x] + carry;
        __syncthreads();
        if (threadIdx.x == 0) carry += sh[1023];
        __syncthreads();
    }
}

__global__ void dinv_kernel(const int* __restrict__ deg, float* __restrict__ dinv, int n) {
    int i = blockIdx.x * blockDim.x + threadIdx.x;
    if (i < n) dinv[i] = rsqrtf((float)deg[i] + 1.0f);
}

__global__ void copy_int_kernel(const int* __restrict__ a, int* __restrict__ b, int n) {
    int i = blockIdx.x * blockDim.x + threadIdx.x;
    if (i < n) b[i] = a[i];
}

__global__ void fill_kernel(const int* __restrict__ src, const int* __restrict__ dst,
                            const float* __restrict__ dinv, int* __restrict__ cursor,
                            int* __restrict__ csr_src, float* __restrict__ csr_w, int E) {
    int e = blockIdx.x * blockDim.x + threadIdx.x;
    if (e < E) {
        int s = src[e], d = dst[e];
        int p = atomicAdd(&cursor[d], 1);
        csr_src[p] = s;
        csr_w[p]   = dinv[s] * dinv[d];
    }
}

// ---------------- weight split: W[k][c] -> WhT/WlT [c][k] bf16, zero-padded ----------------
__global__ void splitw_kernel(const float* __restrict__ W, u16* __restrict__ WhT,
                              u16* __restrict__ WlT, int K, int M, int Kp, int total) {
    int t = blockIdx.x * blockDim.x + threadIdx.x;
    if (t >= total) return;
    int c = t / Kp, k = t - c * Kp;
    float x = (c < M && k < K) ? W[(size_t)k * M + c] : 0.f;
    unsigned u = __float_as_uint(x);
    WhT[t] = (u16)(u >> 16);                                   // truncate -> hi
    float lo = x - __uint_as_float(u & 0xFFFF0000u);
    WlT[t] = (u16)(__float_as_uint(lo) >> 16);                 // truncate -> lo
}

// ---------------- MFMA GEMM: C = cAB*(A@W) + cA*A + bias ----------------
// A fp32 [n][K]; W given as pre-split/transposed bf16 WhT/WlT [Mp][Kp] (zero-padded).
// Markidis 3-term: AhWh + AhWl + AlWh, fp32 accumulate. 64x64 tile, 4 waves (2x2 of 32x32).
__global__ __launch_bounds__(256)
void gemm_mfma_kernel(const float* __restrict__ A, const u16* __restrict__ WhT,
                      const u16* __restrict__ WlT, float* __restrict__ C,
                      int n, int K, int M, int Kp,
                      float cAB, float cA, const float* __restrict__ bias) {
    // 40 u16 per row (80B): 16B-aligned frag reads, near-conflict-free banks
    __shared__ u16 sAh[64 * 40], sAl[64 * 40], sWh[64 * 40], sWl[64 * 40];
    const int tid = threadIdx.x;
    const int rowBase = blockIdx.y * 64;
    const int colBase = blockIdx.x * 64;
    const int lane = tid & 63, wid = tid >> 6;
    const int wr = (wid >> 1) * 32, wc = (wid & 1) * 32;
    const int fr = lane & 15, ko = (lane >> 4) * 8;
    const int wsc = tid >> 2, wsk = (tid & 3) * 8;   // W staging coords

    f32x4 acc[2][2] = {};

    for (int k0 = 0; k0 < Kp; k0 += 32) {
        // stage W tiles (straight bf16 copy; arena is padded so no guards)
        {
            size_t g = (size_t)(colBase + wsc) * Kp + k0 + wsk;
            *(uint4*)&sWh[wsc * 40 + wsk] = *(const uint4*)&WhT[g];
            *(uint4*)&sWl[wsc * 40 + wsk] = *(const uint4*)&WlT[g];
        }
        // stage A tile: fp32 -> split bf16 hi/lo
        const bool fullk = (k0 + 32 <= K);
        for (int s = tid; s < 512; s += 256) {
            int r = s >> 3, kb = (s & 7) * 4;
            int gr = rowBase + r, kk = k0 + kb;
            float x0 = 0.f, x1 = 0.f, x2 = 0.f, x3 = 0.f;
            if (gr < n) {
                const float* ap = A + (size_t)gr * K + kk;
                if (fullk) { float4 v = *(const float4*)ap; x0 = v.x; x1 = v.y; x2 = v.z; x3 = v.w; }
                else {
                    if (kk     < K) x0 = ap[0];
                    if (kk + 1 < K) x1 = ap[1];
                    if (kk + 2 < K) x2 = ap[2];
                    if (kk + 3 < K) x3 = ap[3];
                }
            }
            unsigned u0 = __float_as_uint(x0), u1 = __float_as_uint(x1);
            unsigned u2 = __float_as_uint(x2), u3 = __float_as_uint(x3);
            uint2 hp; hp.x = (u1 & 0xFFFF0000u) | (u0 >> 16);
                      hp.y = (u3 & 0xFFFF0000u) | (u2 >> 16);
            float l0 = x0 - __uint_as_float(u0 & 0xFFFF0000u);
            float l1 = x1 - __uint_as_float(u1 & 0xFFFF0000u);
            float l2 = x2 - __uint_as_float(u2 & 0xFFFF0000u);
            float l3 = x3 - __uint_as_float(u3 & 0xFFFF0000u);
            uint2 lp; lp.x = (__float_as_uint(l1) & 0xFFFF0000u) | (__float_as_uint(l0) >> 16);
                      lp.y = (__float_as_uint(l3) & 0xFFFF0000u) | (__float_as_uint(l2) >> 16);
            *(uint2*)&sAh[r * 40 + kb] = hp;
            *(uint2*)&sAl[r * 40 + kb] = lp;
        }
        __syncthreads();

        short8 ah[2], al[2], bh[2], bl[2];
        ah[0] = *(const short8*)&sAh[(wr +      fr) * 40 + ko];
        ah[1] = *(const short8*)&sAh[(wr + 16 + fr) * 40 + ko];
        al[0] = *(const short8*)&sAl[(wr +      fr) * 40 + ko];
        al[1] = *(const short8*)&sAl[(wr + 16 + fr) * 40 + ko];
        bh[0] = *(const short8*)&sWh[(wc +      fr) * 40 + ko];
        bh[1] = *(const short8*)&sWh[(wc + 16 + fr) * 40 + ko];
        bl[0] = *(const short8*)&sWl[(wc +      fr) * 40 + ko];
        bl[1] = *(const short8*)&sWl[(wc + 16 + fr) * 40 + ko];
#pragma unroll
        for (int i = 0; i < 2; i++)
#pragma unroll
            for (int j = 0; j < 2; j++) {
                acc[i][j] = __builtin_amdgcn_mfma_f32_16x16x32_bf16(al[i], bh[j], acc[i][j], 0, 0, 0);
                acc[i][j] = __builtin_amdgcn_mfma_f32_16x16x32_bf16(ah[i], bl[j], acc[i][j], 0, 0, 0);
                acc[i][j] = __builtin_amdgcn_mfma_f32_16x16x32_bf16(ah[i], bh[j], acc[i][j], 0, 0, 0);
            }
        __syncthreads();
    }

    // epilogue: C/D layout col=lane&15, row=(lane>>4)*4+q  [m89-verified]
#pragma unroll
    for (int i = 0; i < 2; i++)
#pragma unroll
        for (int j = 0; j < 2; j++) {
            int row0 = rowBase + wr + i * 16 + (lane >> 4) * 4;
            int col  = colBase + wc + j * 16 + fr;
            if (col >= M) continue;
            float bv = bias ? bias[col] : 0.f;
#pragma unroll
            for (int q = 0; q < 4; q++) {
                int r = row0 + q;
                if (r >= n) break;
                float v = cAB * acc[i][j][q] + bv;
                if (cA != 0.f) v += cA * A[(size_t)r * K + col];  // only when M==K
                C[(size_t)r * M + col] = v;
            }
        }
}

// ---------------- prop: out = cP*(D^-1/2 A D^-1/2 h) + cH*h + bias ----------------
__global__ __launch_bounds__(256)
void prop_kernel(const float* __restrict__ h, float* __restrict__ out,
                 const int* __restrict__ rowptr, const int* __restrict__ csr_src,
                 const float* __restrict__ csr_w, const float* __restrict__ dinv,
                 const float* __restrict__ bias, int n, int D4, float cP, float cH) {
    int i = (blockIdx.x * blockDim.x + threadIdx.x) >> 6;
    int lane = threadIdx.x & 63;
    if (i >= n) return;
    const float4* h4 = (const float4*)h;
    int c0 = lane, c1 = lane + 64;
    bool a0 = c0 < D4, a1 = c1 < D4;
    float4 acc0 = {0, 0, 0, 0}, acc1 = {0, 0, 0, 0};
    float sw = dinv[i] * dinv[i];
    long bi = (long)i * D4;
    if (a0) { float4 v = h4[bi + c0]; acc0.x = sw * v.x; acc0.y = sw * v.y; acc0.z = sw * v.z; acc0.w = sw * v.w; }
    if (a1) { float4 v = h4[bi + c1]; acc1.x = sw * v.x; acc1.y = sw * v.y; acc1.z = sw * v.z; acc1.w = sw * v.w; }
    int p0 = rowptr[i], p1 = rowptr[i + 1];
    for (int p = p0; p < p1; ++p) {
        int s = csr_src[p];
        float w = csr_w[p];
        long bs = (long)s * D4;
        if (a0) { float4 v = h4[bs + c0]; acc0.x += w * v.x; acc0.y += w * v.y; acc0.z += w * v.z; acc0.w += w * v.w; }
        if (a1) { float4 v = h4[bs + c1]; acc1.x += w * v.x; acc1.y += w * v.y; acc1.z += w * v.z; acc1.w += w * v.w; }
    }
    float4* o4 = (float4*)out;
    if (a0) {
        float4 r = {cP * acc0.x, cP * acc0.y, cP * acc0.z, cP * acc0.w};
        if (cH != 0.f) { float4 v = h4[bi + c0]; r.x += cH * v.x; r.y += cH * v.y; r.z += cH * v.z; r.w += cH * v.w; }
        if (bias) { float4 b = ((const float4*)bias)[c0]; r.x += b.x; r.y += b.y; r.z += b.z; r.w += b.w; }
        o4[bi + c0] = r;
    }
    if (a1) {
        float4 r = {cP * acc1.x, cP * acc1.y, cP * acc1.z, cP * acc1.w};
        if (cH != 0.f) { float4 v = h4[bi + c1]; r.x += cH * v.x; r.y += cH * v.y; r.z += cH * v.z; r.w += cH * v.w; }
        if (bias) { float4 b = ((const float4*)bias)[c1]; r.x += b.x; r.y += b.y; r.z += b.z; r.w += b.w; }
        o4[bi + c1] = r;
    }
}

// ---------------- GATv2 ----------------
__device__ inline float lrelu(float x) { return x > 0.f ? x : NEG_SLOPE * x; }

__global__ __launch_bounds__(256)
void gat_logits_kernel(const float* __restrict__ xl, const float* __restrict__ xr,
                       const float* __restrict__ att, const int* __restrict__ rowptr,
                       const int* __restrict__ csr_src, float* __restrict__ logits,
                       float* __restrict__ self_logits, int n) {
    int t = blockIdx.x * blockDim.x + threadIdx.x;
    int i = t >> 1, hh = t & 1;
    if (i >= n) return;
    float4 attv[8], xrv[8];
    const float4* att4 = (const float4*)att;
    const float4* xr4 = (const float4*)xr;
#pragma unroll
    for (int c = 0; c < 8; c++) {
        attv[c] = att4[hh * 8 + c];
        xrv[c]  = xr4[(long)i * 16 + hh * 8 + c];
    }
    const float4* xl4 = (const float4*)xl;
    {
        float s = 0.f;
        long b = (long)i * 16 + hh * 8;
#pragma unroll
        for (int c = 0; c < 8; c++) {
            float4 e = xl4[b + c];
            s += lrelu(e.x + xrv[c].x) * attv[c].x;
            s += lrelu(e.y + xrv[c].y) * attv[c].y;
            s += lrelu(e.z + xrv[c].z) * attv[c].z;
            s += lrelu(e.w + xrv[c].w) * attv[c].w;
        }
        self_logits[i * 2 + hh] = s;
    }
    int p0 = rowptr[i], p1 = rowptr[i + 1];
    for (int p = p0; p < p1; ++p) {
        int sn = csr_src[p];
        long b = (long)sn * 16 + hh * 8;
        float s = 0.f;
#pragma unroll
        for (int c = 0; c < 8; c++) {
            float4 e = xl4[b + c];
            s += lrelu(e.x + xrv[c].x) * attv[c].x;
            s += lrelu(e.y + xrv[c].y) * attv[c].y;
            s += lrelu(e.z + xrv[c].z) * attv[c].z;
            s += lrelu(e.w + xrv[c].w) * attv[c].w;
        }
        logits[(long)p * 2 + hh] = s;
    }
}

__global__ __launch_bounds__(256)
void gat_mden_kernel(const float* __restrict__ logits, const float* __restrict__ self_logits,
                     const int* __restrict__ rowptr, float* __restrict__ m_arr,
                     float* __restrict__ den_arr, int n) {
    int t = blockIdx.x * blockDim.x + threadIdx.x;
    int i = t >> 1, hh = t & 1;
    if (i >= n) return;
    int p0 = rowptr[i], p1 = rowptr[i + 1];
    float m = self_logits[i * 2 + hh];
    for (int p = p0; p < p1; ++p) m = fmaxf(m, logits[(long)p * 2 + hh]);
    float den = expf(self_logits[i * 2 + hh] - m);
    for (int p = p0; p < p1; ++p) den += expf(logits[(long)p * 2 + hh] - m);
    m_arr[i * 2 + hh] = m;
    den_arr[i * 2 + hh] = den;
}

__global__ __launch_bounds__(256)
void gat_out_kernel(const float* __restrict__ xl, const int* __restrict__ rowptr,
                    const int* __restrict__ csr_src, const float* __restrict__ logits,
                    const float* __restrict__ self_logits, const float* __restrict__ m_arr,
                    const float* __restrict__ den_arr, const float* __restrict__ bias,
                    float* __restrict__ out, int n) {
    int i = (blockIdx.x * blockDim.x + threadIdx.x) >> 6;
    int lane = threadIdx.x & 63;
    if (i >= n) return;
    int hh = lane >> 5;
    float m = m_arr[i * 2 + hh];
    float inv = 1.f / (den_arr[i * 2 + hh] + 1e-16f);
    float acc = expf(self_logits[i * 2 + hh] - m) * inv * xl[(long)i * 64 + lane];
    int p0 = rowptr[i], p1 = rowptr[i + 1];
    for (int p = p0; p < p1; ++p) {
        float w = expf(logits[(long)p * 2 + hh] - m) * inv;
        acc += w * xl[(long)csr_src[p] * 64 + lane];
    }
    out[(long)i * 64 + lane] = fmaxf(acc + bias[lane], 0.f);  // bias + ReLU fused
}

__global__ void sigmoid_kernel(const float* __restrict__ in, float* __restrict__ out, int n4) {
    int i = blockIdx.x * blockDim.x + threadIdx.x;
    if (i < n4) {
        float4 v = ((const float4*)in)[i];
        float4 r;
        r.x = 1.f / (1.f + expf(-v.x));
        r.y = 1.f / (1.f + expf(-v.y));
        r.z = 1.f / (1.f + expf(-v.z));
        r.w = 1.f / (1.f + expf(-v.w));
        ((float4*)out)[i] = r;
    }
}

// ---------------- launch ----------------
extern "C" void kernel_launch(void* const* d_in, const int* in_sizes, int n_in,
                              void* d_out, int out_size, void* d_ws, size_t ws_size,
                              hipStream_t stream) {
    const int N = NN;
    const int E = in_sizes[1] / 2;

    // weight specs in gemm-call order
    struct WSpec { int idx; int K, M; };
    const WSpec wspec[11] = {
        {2, 300, 256},   // W1
        {4, 256, 256},   // W2
        {5, 256, 128},   // W3
        {7, 128, 64},    // W4
        {9, 64, 32},     // W5
        {11, 32, 64},    // Wl
        {12, 32, 64},    // Wr
        {15, 64, 128},   // Wd1
        {17, 128, 256},  // Wd2
        {19, 256, 256},  // Wd3
        {20, 256, 300},  // Wd4
    };
    size_t arena_elems = 0;
    int kp[11], mp[11];
    size_t woff[11];
    for (int i = 0; i < 11; i++) {
        kp[i] = (wspec[i].K + 31) & ~31;
        mp[i] = (wspec[i].M + 63) & ~63;
        woff[i] = arena_elems;
        arena_elems += (size_t)2 * mp[i] * kp[i];  // hi + lo
    }

    // workspace requirement guard (clean fail instead of OOB fault)
    size_t need = 0;
    need += (size_t)N * 304 * 4 * 2;     // bufA, bufB
    need += (size_t)E * 4;               // csr_w
    need += (size_t)E * 2 * 4;           // logits
    need += (size_t)N * 2 * 4 * 3;       // self_logits, m_arr, den_arr
    need += (size_t)N * 4;               // dinv
    need += (size_t)N * 4;               // deg
    need += (size_t)(N + 4) * 4;         // rowptr
    need += (size_t)N * 4;               // cursor
    need += (size_t)E * 4;               // csr_src
    need += arena_elems * 2 + 64;        // bf16 weight arena + align slack
    if (ws_size < need) return;

    const float* x      = (const float*)d_in[0];
    const int*   ei     = (const int*)d_in[1];
    const int*   e_src  = ei;
    const int*   e_dst  = ei + E;
    const float* b1  = (const float*)d_in[3];
    const float* b3  = (const float*)d_in[6];
    const float* b4  = (const float*)d_in[8];
    const float* b5  = (const float*)d_in[10];
    const float* attw= (const float*)d_in[13];
    const float* bg  = (const float*)d_in[14];
    const float* bd1 = (const float*)d_in[16];
    const float* bd2 = (const float*)d_in[18];
    const float* bd4 = (const float*)d_in[21];

    // workspace carve-up
    char* w = (char*)d_ws;
    float* bufA = (float*)w;                 w += (size_t)N * 304 * 4;
    float* bufB = (float*)w;                 w += (size_t)N * 304 * 4;
    float* csr_w = (float*)w;                w += (size_t)E * 4;
    float* logits = (float*)w;               w += (size_t)E * 2 * 4;
    float* self_logits = (float*)w;          w += (size_t)N * 2 * 4;
    float* m_arr = (float*)w;                w += (size_t)N * 2 * 4;
    float* den_arr = (float*)w;              w += (size_t)N * 2 * 4;
    float* dinv = (float*)w;                 w += (size_t)N * 4;
    int* deg = (int*)w;                      w += (size_t)N * 4;
    int* rowptr = (int*)w;                   w += (size_t)(N + 4) * 4;
    int* cursor = (int*)w;                   w += (size_t)N * 4;
    int* csr_src = (int*)w;                  w += (size_t)E * 4;
    w = (char*)(((size_t)w + 63) & ~(size_t)63);
    u16* arena = (u16*)w;                    w += arena_elems * 2;
    float* T = (float*)d_out;                // GEMM tmp buffer (N x <=300)

    int nb_e = (E + 255) / 256;
    int nb_n = (N + 255) / 256;
    int nb_wave = (N + 3) / 4;
    int nb_2n = (2 * N + 255) / 256;

    // --- weight split/transpose (tiny) ---
    for (int i = 0; i < 11; i++) {
        int total = mp[i] * kp[i];
        splitw_kernel<<<(total + 255) / 256, 256, 0, stream>>>(
            (const float*)d_in[wspec[i].idx], arena + woff[i], arena + woff[i] + total,
            wspec[i].K, wspec[i].M, kp[i], total);
    }

    // --- CSR build ---
    hipMemsetAsync(deg, 0, (size_t)N * 4, stream);
    hist_kernel<<<nb_e, 256, 0, stream>>>(e_dst, deg, E);
    scan_kernel<<<1, 1024, 0, stream>>>(deg, rowptr, N);
    dinv_kernel<<<nb_n, 256, 0, stream>>>(deg, dinv, N);
    copy_int_kernel<<<nb_n, 256, 0, stream>>>(rowptr, cursor, N);
    fill_kernel<<<nb_e, 256, 0, stream>>>(e_src, e_dst, dinv, cursor, csr_src, csr_w, E);

    auto gemm = [&](int wi, const float* A, float* C, float cAB, float cA, const float* bias) {
        int K = wspec[wi].K, M = wspec[wi].M;
        int total = mp[wi] * kp[wi];
        dim3 grid((M + 63) / 64, (N + 63) / 64);  // col-blocks fastest: A-tile L2/L3 reuse
        gemm_mfma_kernel<<<grid, 256, 0, stream>>>(A, arena + woff[wi], arena + woff[wi] + total,
                                                   C, N, K, M, kp[wi], cAB, cA, bias);
    };
    auto prop = [&](const float* h, float* out, int D, float cP, float cH, const float* bias) {
        prop_kernel<<<nb_wave, 256, 0, stream>>>(h, out, rowptr, csr_src, csr_w, dinv,
                                                 bias, N, D / 4, cP, cH);
    };

    // L1: gcn(x, W1, b1) -> A [256]
    gemm(0, x, T, 1.f, 0.f, nullptr);
    prop(T, bufA, 256, 1.f, 0.f, b1);
    // L2: gcn2(A, W2) -> A  (hp in B)
    prop(bufA, bufB, 256, 1.f - ALPHA_C, ALPHA_C, nullptr);
    gemm(1, bufB, bufA, BETA_C, 1.f - BETA_C, nullptr);
    // L3: gcn(A, W3, b3) -> B [128]
    gemm(2, bufA, T, 1.f, 0.f, nullptr);
    prop(T, bufB, 128, 1.f, 0.f, b3);
    // L4: gcn(B, W4, b4) -> A [64]
    gemm(3, bufB, T, 1.f, 0.f, nullptr);
    prop(T, bufA, 64, 1.f, 0.f, b4);
    // L5: gcn(A, W5, b5) -> B [32]
    gemm(4, bufA, T, 1.f, 0.f, nullptr);
    prop(T, bufB, 32, 1.f, 0.f, b5);
    // GAT: xl = B@Wl -> A, xr = B@Wr -> T
    gemm(5, bufB, bufA, 1.f, 0.f, nullptr);
    gemm(6, bufB, T, 1.f, 0.f, nullptr);
    gat_logits_kernel<<<nb_2n, 256, 0, stream>>>(bufA, T, attw, rowptr, csr_src,
                                                 logits, self_logits, N);
    gat_mden_kernel<<<nb_2n, 256, 0, stream>>>(logits, self_logits, rowptr, m_arr, den_arr, N);
    gat_out_kernel<<<nb_wave, 256, 0, stream>>>(bufA, rowptr, csr_src, logits, self_logits,
                                                m_arr, den_arr, bg, bufB, N);  // + ReLU -> B [64]
    // dec1: gcn(B, Wd1, bd1) -> A [128]
    gemm(7, bufB, T, 1.f, 0.f, nullptr);
    prop(T, bufA, 128, 1.f, 0.f, bd1);
    // dec2: gcn(A, Wd2, bd2) -> B [256]
    gemm(8, bufA, T, 1.f, 0.f, nullptr);
    prop(T, bufB, 256, 1.f, 0.f, bd2);
    // dec3: gcn2(B, Wd3) -> B (hp in A)
    prop(bufB, bufA, 256, 1.f - ALPHA_C, ALPHA_C, nullptr);
    gemm(9, bufA, bufB, BETA_C, 1.f - BETA_C, nullptr);
    // dec4: gcn(B, Wd4, bd4) -> A [300]
    gemm(10, bufB, T, 1.f, 0.f, nullptr);
    prop(T, bufA, FIN, 1.f, 0.f, bd4);
    // sigmoid -> d_out
    sigmoid_kernel<<<(out_size / 4 + 255) / 256, 256, 0, stream>>>(bufA, (float*)d_out, out_size / 4);
}

// Round 7
// 1707.545 us; speedup vs baseline: 1.3896x; 1.1237x over previous
//
#include <hip/hip_runtime.h>
#include <math.h>

#define NN 50000
#define FIN 300
#define SS 304   // fp16 shadow row stride (halves)
constexpr float ALPHA_C = 0.5f;
constexpr float BETA_C  = 0.09531017980432486f;  // log(1.1)
constexpr float NEG_SLOPE = 0.2f;

typedef unsigned short u16;
typedef __attribute__((ext_vector_type(8))) short short8;
typedef __attribute__((ext_vector_type(4))) float f32x4;
typedef _Float16 hf4 __attribute__((ext_vector_type(4)));

// ---------------- CSR build ----------------
__global__ void hist_kernel(const int* __restrict__ dst, int* __restrict__ deg, int E) {
    int e = blockIdx.x * blockDim.x + threadIdx.x;
    if (e < E) atomicAdd(&deg[dst[e]], 1);
}

__global__ void scan_kernel(const int* __restrict__ deg, int* __restrict__ rowptr, int n) {
    __shared__ int sh[1024];
    __shared__ int carry;
    if (threadIdx.x == 0) { carry = 0; rowptr[0] = 0; }
    __syncthreads();
    for (int base = 0; base < n; base += 1024) {
        int i = base + threadIdx.x;
        int v = (i < n) ? deg[i] : 0;
        sh[threadIdx.x] = v;
        __syncthreads();
        for (int off = 1; off < 1024; off <<= 1) {
            int t = (threadIdx.x >= off) ? sh[threadIdx.x - off] : 0;
            __syncthreads();
            sh[threadIdx.x] += t;
            __syncthreads();
        }
        if (i < n) rowptr[i + 1] = sh[threadIdx.x] + carry;
        __syncthreads();
        if (threadIdx.x == 0) carry += sh[1023];
        __syncthreads();
    }
}

__global__ void dinv_kernel(const int* __restrict__ deg, float* __restrict__ dinv, int n) {
    int i = blockIdx.x * blockDim.x + threadIdx.x;
    if (i < n) dinv[i] = rsqrtf((float)deg[i] + 1.0f);
}

__global__ void copy_int_kernel(const int* __restrict__ a, int* __restrict__ b, int n) {
    int i = blockIdx.x * blockDim.x + threadIdx.x;
    if (i < n) b[i] = a[i];
}

__global__ void fill_kernel(const int* __restrict__ src, const int* __restrict__ dst,
                            const float* __restrict__ dinv, int* __restrict__ cursor,
                            int* __restrict__ csr_src, float* __restrict__ csr_w, int E) {
    int e = blockIdx.x * blockDim.x + threadIdx.x;
    if (e < E) {
        int s = src[e], d = dst[e];
        int p = atomicAdd(&cursor[d], 1);
        csr_src[p] = s;
        csr_w[p]   = dinv[s] * dinv[d];
    }
}

// ---------------- weight split: W[k][c] -> WhT/WlT [c][k] bf16, zero-padded ----------------
__global__ void splitw_kernel(const float* __restrict__ W, u16* __restrict__ WhT,
                              u16* __restrict__ WlT, int K, int M, int Kp, int total) {
    int t = blockIdx.x * blockDim.x + threadIdx.x;
    if (t >= total) return;
    int c = t / Kp, k = t - c * Kp;
    float x = (c < M && k < K) ? W[(size_t)k * M + c] : 0.f;
    unsigned u = __float_as_uint(x);
    WhT[t] = (u16)(u >> 16);
    float lo = x - __uint_as_float(u & 0xFFFF0000u);
    WlT[t] = (u16)(__float_as_uint(lo) >> 16);
}

// ---------------- MFMA GEMM: C = cAB*(A@W) + cA*A + bias; optional fp16 shadow ----------------
__global__ __launch_bounds__(256)
void gemm_mfma_kernel(const float* __restrict__ A, const u16* __restrict__ WhT,
                      const u16* __restrict__ WlT, float* __restrict__ C,
                      _Float16* __restrict__ Cs, int n, int K, int M, int Kp,
                      float cAB, float cA, const float* __restrict__ bias) {
    __shared__ u16 sAh[64 * 40], sAl[64 * 40], sWh[64 * 40], sWl[64 * 40];
    const int tid = threadIdx.x;
    const int rowBase = blockIdx.y * 64;
    const int colBase = blockIdx.x * 64;
    const int lane = tid & 63, wid = tid >> 6;
    const int wr = (wid >> 1) * 32, wc = (wid & 1) * 32;
    const int fr = lane & 15, ko = (lane >> 4) * 8;
    const int wsc = tid >> 2, wsk = (tid & 3) * 8;

    f32x4 acc[2][2] = {};

    for (int k0 = 0; k0 < Kp; k0 += 32) {
        {
            size_t g = (size_t)(colBase + wsc) * Kp + k0 + wsk;
            *(uint4*)&sWh[wsc * 40 + wsk] = *(const uint4*)&WhT[g];
            *(uint4*)&sWl[wsc * 40 + wsk] = *(const uint4*)&WlT[g];
        }
        const bool fullk = (k0 + 32 <= K);
        for (int s = tid; s < 512; s += 256) {
            int r = s >> 3, kb = (s & 7) * 4;
            int gr = rowBase + r, kk = k0 + kb;
            float x0 = 0.f, x1 = 0.f, x2 = 0.f, x3 = 0.f;
            if (gr < n) {
                const float* ap = A + (size_t)gr * K + kk;
                if (fullk) { float4 v = *(const float4*)ap; x0 = v.x; x1 = v.y; x2 = v.z; x3 = v.w; }
                else {
                    if (kk     < K) x0 = ap[0];
                    if (kk + 1 < K) x1 = ap[1];
                    if (kk + 2 < K) x2 = ap[2];
                    if (kk + 3 < K) x3 = ap[3];
                }
            }
            unsigned u0 = __float_as_uint(x0), u1 = __float_as_uint(x1);
            unsigned u2 = __float_as_uint(x2), u3 = __float_as_uint(x3);
            uint2 hp; hp.x = (u1 & 0xFFFF0000u) | (u0 >> 16);
                      hp.y = (u3 & 0xFFFF0000u) | (u2 >> 16);
            float l0 = x0 - __uint_as_float(u0 & 0xFFFF0000u);
            float l1 = x1 - __uint_as_float(u1 & 0xFFFF0000u);
            float l2 = x2 - __uint_as_float(u2 & 0xFFFF0000u);
            float l3 = x3 - __uint_as_float(u3 & 0xFFFF0000u);
            uint2 lp; lp.x = (__float_as_uint(l1) & 0xFFFF0000u) | (__float_as_uint(l0) >> 16);
                      lp.y = (__float_as_uint(l3) & 0xFFFF0000u) | (__float_as_uint(l2) >> 16);
            *(uint2*)&sAh[r * 40 + kb] = hp;
            *(uint2*)&sAl[r * 40 + kb] = lp;
        }
        __syncthreads();

        short8 ah[2], al[2], bh[2], bl[2];
        ah[0] = *(const short8*)&sAh[(wr +      fr) * 40 + ko];
        ah[1] = *(const short8*)&sAh[(wr + 16 + fr) * 40 + ko];
        al[0] = *(const short8*)&sAl[(wr +      fr) * 40 + ko];
        al[1] = *(const short8*)&sAl[(wr + 16 + fr) * 40 + ko];
        bh[0] = *(const short8*)&sWh[(wc +      fr) * 40 + ko];
        bh[1] = *(const short8*)&sWh[(wc + 16 + fr) * 40 + ko];
        bl[0] = *(const short8*)&sWl[(wc +      fr) * 40 + ko];
        bl[1] = *(const short8*)&sWl[(wc + 16 + fr) * 40 + ko];
#pragma unroll
        for (int i = 0; i < 2; i++)
#pragma unroll
            for (int j = 0; j < 2; j++) {
                acc[i][j] = __builtin_amdgcn_mfma_f32_16x16x32_bf16(al[i], bh[j], acc[i][j], 0, 0, 0);
                acc[i][j] = __builtin_amdgcn_mfma_f32_16x16x32_bf16(ah[i], bl[j], acc[i][j], 0, 0, 0);
                acc[i][j] = __builtin_amdgcn_mfma_f32_16x16x32_bf16(ah[i], bh[j], acc[i][j], 0, 0, 0);
            }
        __syncthreads();
    }

#pragma unroll
    for (int i = 0; i < 2; i++)
#pragma unroll
        for (int j = 0; j < 2; j++) {
            int row0 = rowBase + wr + i * 16 + (lane >> 4) * 4;
            int col  = colBase + wc + j * 16 + fr;
            if (col >= M) continue;
            float bv = bias ? bias[col] : 0.f;
#pragma unroll
            for (int q = 0; q < 4; q++) {
                int r = row0 + q;
                if (r >= n) break;
                float v = cAB * acc[i][j][q] + bv;
                if (cA != 0.f) v += cA * A[(size_t)r * K + col];
                C[(size_t)r * M + col] = v;
                if (Cs) Cs[(size_t)r * SS + col] = (_Float16)v;
            }
        }
}

// ---- prop: out = cP*(D^-1/2 A D^-1/2 h) + cH*h + bias ; gather from fp16 shadow ----
__global__ __launch_bounds__(256)
void prop_kernel(const float* __restrict__ h, const _Float16* __restrict__ hs,
                 float* __restrict__ out, _Float16* __restrict__ outs,
                 const int* __restrict__ rowptr, const int* __restrict__ csr_src,
                 const float* __restrict__ csr_w, const float* __restrict__ dinv,
                 const float* __restrict__ bias, int n, int D, float cP, float cH) {
    int i = (blockIdx.x * blockDim.x + threadIdx.x) >> 6;
    int lane = threadIdx.x & 63;
    int c = lane * 4;
    if (i >= n || c >= D) return;
    int D4 = D >> 2;
    long bi = (long)i * D4 + lane;
    const float4* h4 = (const float4*)h;
    float4 hv = h4[bi];
    float sw = dinv[i] * dinv[i];
    float4 acc = {sw * hv.x, sw * hv.y, sw * hv.z, sw * hv.w};
    int p0 = rowptr[i], p1 = rowptr[i + 1];
    for (int p = p0; p < p1; ++p) {
        int s = csr_src[p];
        float w = csr_w[p];
        hf4 v = *(const hf4*)&hs[(size_t)s * SS + c];
        acc.x += w * (float)v[0];
        acc.y += w * (float)v[1];
        acc.z += w * (float)v[2];
        acc.w += w * (float)v[3];
    }
    float4 r = {cP * acc.x, cP * acc.y, cP * acc.z, cP * acc.w};
    if (cH != 0.f) { r.x += cH * hv.x; r.y += cH * hv.y; r.z += cH * hv.z; r.w += cH * hv.w; }
    if (bias) { float4 b = ((const float4*)bias)[lane]; r.x += b.x; r.y += b.y; r.z += b.z; r.w += b.w; }
    ((float4*)out)[bi] = r;
    if (outs) {
        hf4 o; o[0] = (_Float16)r.x; o[1] = (_Float16)r.y; o[2] = (_Float16)r.z; o[3] = (_Float16)r.w;
        *(hf4*)&outs[(size_t)i * SS + c] = o;
    }
}

// ---------------- GATv2 ----------------
__device__ inline float lrelu(float x) { return x > 0.f ? x : NEG_SLOPE * x; }

__global__ __launch_bounds__(256)
void gat_logits_kernel(const float* __restrict__ xl, const _Float16* __restrict__ xls,
                       const float* __restrict__ xr, const float* __restrict__ att,
                       const int* __restrict__ rowptr, const int* __restrict__ csr_src,
                       float* __restrict__ logits, float* __restrict__ self_logits, int n) {
    int t = blockIdx.x * blockDim.x + threadIdx.x;
    int i = t >> 1, hh = t & 1;
    if (i >= n) return;
    float4 attv[8], xrv[8];
    const float4* att4 = (const float4*)att;
    const float4* xr4 = (const float4*)xr;
#pragma unroll
    for (int c = 0; c < 8; c++) {
        attv[c] = att4[hh * 8 + c];
        xrv[c]  = xr4[(long)i * 16 + hh * 8 + c];
    }
    // self edge from fp32 xl
    {
        const float4* xl4 = (const float4*)xl;
        float s = 0.f;
        long b = (long)i * 16 + hh * 8;
#pragma unroll
        for (int c = 0; c < 8; c++) {
            float4 e = xl4[b + c];
            s += lrelu(e.x + xrv[c].x) * attv[c].x;
            s += lrelu(e.y + xrv[c].y) * attv[c].y;
            s += lrelu(e.z + xrv[c].z) * attv[c].z;
            s += lrelu(e.w + xrv[c].w) * attv[c].w;
        }
        self_logits[i * 2 + hh] = s;
    }
    int p0 = rowptr[i], p1 = rowptr[i + 1];
    for (int p = p0; p < p1; ++p) {
        int sn = csr_src[p];
        size_t b = (size_t)sn * SS + hh * 32;
        float s = 0.f;
#pragma unroll
        for (int c = 0; c < 8; c++) {
            hf4 e = *(const hf4*)&xls[b + c * 4];
            s += lrelu((float)e[0] + xrv[c].x) * attv[c].x;
            s += lrelu((float)e[1] + xrv[c].y) * attv[c].y;
            s += lrelu((float)e[2] + xrv[c].z) * attv[c].z;
            s += lrelu((float)e[3] + xrv[c].w) * attv[c].w;
        }
        logits[(long)p * 2 + hh] = s;
    }
}

__global__ __launch_bounds__(256)
void gat_mden_kernel(const float* __restrict__ logits, const float* __restrict__ self_logits,
                     const int* __restrict__ rowptr, float* __restrict__ m_arr,
                     float* __restrict__ den_arr, int n) {
    int t = blockIdx.x * blockDim.x + threadIdx.x;
    int i = t >> 1, hh = t & 1;
    if (i >= n) return;
    int p0 = rowptr[i], p1 = rowptr[i + 1];
    float m = self_logits[i * 2 + hh];
    for (int p = p0; p < p1; ++p) m = fmaxf(m, logits[(long)p * 2 + hh]);
    float den = expf(self_logits[i * 2 + hh] - m);
    for (int p = p0; p < p1; ++p) den += expf(logits[(long)p * 2 + hh] - m);
    m_arr[i * 2 + hh] = m;
    den_arr[i * 2 + hh] = den;
}

__global__ __launch_bounds__(256)
void gat_out_kernel(const float* __restrict__ xl, const _Float16* __restrict__ xls,
                    const int* __restrict__ rowptr, const int* __restrict__ csr_src,
                    const float* __restrict__ logits, const float* __restrict__ self_logits,
                    const float* __restrict__ m_arr, const float* __restrict__ den_arr,
                    const float* __restrict__ bias, float* __restrict__ out,
                    _Float16* __restrict__ outs, int n) {
    int i = (blockIdx.x * blockDim.x + threadIdx.x) >> 6;
    int lane = threadIdx.x & 63;
    if (i >= n) return;
    int hh = lane >> 5;
    float m = m_arr[i * 2 + hh];
    float inv = 1.f / (den_arr[i * 2 + hh] + 1e-16f);
    float acc = expf(self_logits[i * 2 + hh] - m) * inv * xl[(long)i * 64 + lane];
    int p0 = rowptr[i], p1 = rowptr[i + 1];
    for (int p = p0; p < p1; ++p) {
        float w = expf(logits[(long)p * 2 + hh] - m) * inv;
        acc += w * (float)xls[(size_t)csr_src[p] * SS + lane];
    }
    float r = fmaxf(acc + bias[lane], 0.f);   // bias + ReLU fused
    out[(long)i * 64 + lane] = r;
    outs[(size_t)i * SS + lane] = (_Float16)r;
}

__global__ void sigmoid_kernel(const float* __restrict__ in, float* __restrict__ out, int n4) {
    int i = blockIdx.x * blockDim.x + threadIdx.x;
    if (i < n4) {
        float4 v = ((const float4*)in)[i];
        float4 r;
        r.x = 1.f / (1.f + expf(-v.x));
        r.y = 1.f / (1.f + expf(-v.y));
        r.z = 1.f / (1.f + expf(-v.z));
        r.w = 1.f / (1.f + expf(-v.w));
        ((float4*)out)[i] = r;
    }
}

// ---------------- launch ----------------
extern "C" void kernel_launch(void* const* d_in, const int* in_sizes, int n_in,
                              void* d_out, int out_size, void* d_ws, size_t ws_size,
                              hipStream_t stream) {
    const int N = NN;
    const int E = in_sizes[1] / 2;

    struct WSpec { int idx; int K, M; };
    const WSpec wspec[11] = {
        {2, 300, 256},   // W1
        {4, 256, 256},   // W2
        {5, 256, 128},   // W3
        {7, 128, 64},    // W4
        {9, 64, 32},     // W5
        {11, 32, 64},    // Wl
        {12, 32, 64},    // Wr
        {15, 64, 128},   // Wd1
        {17, 128, 256},  // Wd2
        {19, 256, 256},  // Wd3
        {20, 256, 300},  // Wd4
    };
    size_t arena_elems = 0;
    int kp[11], mp[11];
    size_t woff[11];
    for (int i = 0; i < 11; i++) {
        kp[i] = (wspec[i].K + 31) & ~31;
        mp[i] = (wspec[i].M + 63) & ~63;
        woff[i] = arena_elems;
        arena_elems += (size_t)2 * mp[i] * kp[i];
    }

    size_t need = 0;
    need += (size_t)N * 304 * 4 * 2;     // bufA, bufB
    need += (size_t)N * SS * 2;          // fp16 shadow
    need += (size_t)E * 4;               // csr_w
    need += (size_t)E * 2 * 4;           // logits
    need += (size_t)N * 2 * 4 * 3;       // self_logits, m_arr, den_arr
    need += (size_t)N * 4;               // dinv
    need += (size_t)N * 4;               // deg
    need += (size_t)(N + 4) * 4;         // rowptr
    need += (size_t)N * 4;               // cursor
    need += (size_t)E * 4;               // csr_src
    need += arena_elems * 2 + 128;       // bf16 weight arena + align slack
    if (ws_size < need) return;

    const float* x      = (const float*)d_in[0];
    const int*   ei     = (const int*)d_in[1];
    const int*   e_src  = ei;
    const int*   e_dst  = ei + E;
    const float* b1  = (const float*)d_in[3];
    const float* b3  = (const float*)d_in[6];
    const float* b4  = (const float*)d_in[8];
    const float* b5  = (const float*)d_in[10];
    const float* attw= (const float*)d_in[13];
    const float* bg  = (const float*)d_in[14];
    const float* bd1 = (const float*)d_in[16];
    const float* bd2 = (const float*)d_in[18];
    const float* bd4 = (const float*)d_in[21];

    char* w = (char*)d_ws;
    float* bufA = (float*)w;                 w += (size_t)N * 304 * 4;
    float* bufB = (float*)w;                 w += (size_t)N * 304 * 4;
    _Float16* S = (_Float16*)w;              w += (size_t)N * SS * 2;
    float* csr_w = (float*)w;                w += (size_t)E * 4;
    float* logits = (float*)w;               w += (size_t)E * 2 * 4;
    float* self_logits = (float*)w;          w += (size_t)N * 2 * 4;
    float* m_arr = (float*)w;                w += (size_t)N * 2 * 4;
    float* den_arr = (float*)w;              w += (size_t)N * 2 * 4;
    float* dinv = (float*)w;                 w += (size_t)N * 4;
    int* deg = (int*)w;                      w += (size_t)N * 4;
    int* rowptr = (int*)w;                   w += (size_t)(N + 4) * 4;
    int* cursor = (int*)w;                   w += (size_t)N * 4;
    int* csr_src = (int*)w;                  w += (size_t)E * 4;
    w = (char*)(((size_t)w + 63) & ~(size_t)63);
    u16* arena = (u16*)w;                    w += arena_elems * 2;
    float* T = (float*)d_out;                // GEMM tmp buffer (N x <=300)

    int nb_e = (E + 255) / 256;
    int nb_n = (N + 255) / 256;
    int nb_wave = (N + 3) / 4;
    int nb_2n = (2 * N + 255) / 256;

    for (int i = 0; i < 11; i++) {
        int total = mp[i] * kp[i];
        splitw_kernel<<<(total + 255) / 256, 256, 0, stream>>>(
            (const float*)d_in[wspec[i].idx], arena + woff[i], arena + woff[i] + total,
            wspec[i].K, wspec[i].M, kp[i], total);
    }

    hipMemsetAsync(deg, 0, (size_t)N * 4, stream);
    hist_kernel<<<nb_e, 256, 0, stream>>>(e_dst, deg, E);
    scan_kernel<<<1, 1024, 0, stream>>>(deg, rowptr, N);
    dinv_kernel<<<nb_n, 256, 0, stream>>>(deg, dinv, N);
    copy_int_kernel<<<nb_n, 256, 0, stream>>>(rowptr, cursor, N);
    fill_kernel<<<nb_e, 256, 0, stream>>>(e_src, e_dst, dinv, cursor, csr_src, csr_w, E);

    auto gemm = [&](int wi, const float* A, float* C, float cAB, float cA,
                    const float* bias, bool shadow) {
        int K = wspec[wi].K, M = wspec[wi].M;
        int total = mp[wi] * kp[wi];
        dim3 grid((M + 63) / 64, (N + 63) / 64);
        gemm_mfma_kernel<<<grid, 256, 0, stream>>>(A, arena + woff[wi], arena + woff[wi] + total,
                                                   C, shadow ? S : nullptr,
                                                   N, K, M, kp[wi], cAB, cA, bias);
    };
    auto prop = [&](const float* h, float* out, int D, float cP, float cH,
                    const float* bias, bool shadow) {
        prop_kernel<<<nb_wave, 256, 0, stream>>>(h, S, out, shadow ? S : nullptr,
                                                 rowptr, csr_src, csr_w, dinv,
                                                 bias, N, D, cP, cH);
    };

    // L1: gcn(x, W1, b1) -> A [256]
    gemm(0, x, T, 1.f, 0.f, nullptr, true);
    prop(T, bufA, 256, 1.f, 0.f, b1, true);
    // L2: gcn2(A, W2) -> A
    prop(bufA, bufB, 256, 1.f - ALPHA_C, ALPHA_C, nullptr, false);
    gemm(1, bufB, bufA, BETA_C, 1.f - BETA_C, nullptr, false);
    // L3: gcn(A, W3, b3) -> B [128]
    gemm(2, bufA, T, 1.f, 0.f, nullptr, true);
    prop(T, bufB, 128, 1.f, 0.f, b3, false);
    // L4: gcn(B, W4, b4) -> A [64]
    gemm(3, bufB, T, 1.f, 0.f, nullptr, true);
    prop(T, bufA, 64, 1.f, 0.f, b4, false);
    // L5: gcn(A, W5, b5) -> B [32]
    gemm(4, bufA, T, 1.f, 0.f, nullptr, true);
    prop(T, bufB, 32, 1.f, 0.f, b5, false);
    // GAT: xl = B@Wl -> A (+S), xr = B@Wr -> T
    gemm(5, bufB, bufA, 1.f, 0.f, nullptr, true);
    gemm(6, bufB, T, 1.f, 0.f, nullptr, false);
    gat_logits_kernel<<<nb_2n, 256, 0, stream>>>(bufA, S, T, attw, rowptr, csr_src,
                                                 logits, self_logits, N);
    gat_mden_kernel<<<nb_2n, 256, 0, stream>>>(logits, self_logits, rowptr, m_arr, den_arr, N);
    gat_out_kernel<<<nb_wave, 256, 0, stream>>>(bufA, S, rowptr, csr_src, logits, self_logits,
                                                m_arr, den_arr, bg, bufB, S, N);  // B [64] + S
    // dec1: prop@64 then gemm 64->128 (+bd1)   [prop/gemm commute]
    prop(bufB, bufA, 64, 1.f, 0.f, nullptr, false);
    gemm(7, bufA, T, 1.f, 0.f, bd1, true);
    // dec2: prop@128 then gemm 128->256 (+bd2)
    prop(T, bufB, 128, 1.f, 0.f, nullptr, false);
    gemm(8, bufB, bufA, 1.f, 0.f, bd2, true);
    // dec3: gcn2(A, Wd3) -> A
    prop(bufA, bufB, 256, 1.f - ALPHA_C, ALPHA_C, nullptr, false);
    gemm(9, bufB, bufA, BETA_C, 1.f - BETA_C, nullptr, true);
    // dec4: prop@256 then gemm 256->300 (+bd4)
    prop(bufA, bufB, 256, 1.f, 0.f, nullptr, false);
    gemm(10, bufB, T, 1.f, 0.f, bd4, false);
    // sigmoid in-place on d_out
    sigmoid_kernel<<<(out_size / 4 + 255) / 256, 256, 0, stream>>>(T, (float*)d_out, out_size / 4);
}